// Round 1
// baseline (4541.575 us; speedup 1.0000x reference)
//
#include <hip/hip_runtime.h>

#define NN 50000
#define EE 800000
#define IN_F 256
#define HID_F 256
#define OUT_F 128

// ---------------- GEMM: C[M,Nc] = A[M,K] @ B[K,Nc], row-major, f32 ----------------
__global__ __launch_bounds__(256) void gemm_f32(const float* __restrict__ A,
                                                const float* __restrict__ B,
                                                float* __restrict__ C,
                                                int M, int Nc, int K) {
    const int BM = 64, BN = 64, BK = 32;
    __shared__ float As[BK][BM + 1];
    __shared__ float Bs[BK][BN + 1];
    int bm = blockIdx.y * BM, bn = blockIdx.x * BN;
    int tid = threadIdx.x;
    int tx = tid & 15, ty = tid >> 4;   // 16 x 16
    float acc[4][4] = {};
    for (int k0 = 0; k0 < K; k0 += BK) {
        // A tile: 64x32
        for (int i = tid; i < BM * BK; i += 256) {
            int m = i >> 5, k = i & 31;
            int gm = bm + m;
            As[k][m] = (gm < M) ? A[(size_t)gm * K + k0 + k] : 0.f;
        }
        // B tile: 32x64
        for (int i = tid; i < BK * BN; i += 256) {
            int k = i >> 6, n = i & 63;
            Bs[k][n] = B[(size_t)(k0 + k) * Nc + bn + n];
        }
        __syncthreads();
#pragma unroll
        for (int k = 0; k < BK; k++) {
            float a[4], b[4];
#pragma unroll
            for (int u = 0; u < 4; u++) { a[u] = As[k][ty * 4 + u]; b[u] = Bs[k][tx * 4 + u]; }
#pragma unroll
            for (int i2 = 0; i2 < 4; i2++)
#pragma unroll
                for (int j = 0; j < 4; j++) acc[i2][j] += a[i2] * b[j];
        }
        __syncthreads();
    }
#pragma unroll
    for (int i2 = 0; i2 < 4; i2++) {
        int m = bm + ty * 4 + i2;
        if (m < M) {
#pragma unroll
            for (int j = 0; j < 4; j++) C[(size_t)m * Nc + bn + tx * 4 + j] = acc[i2][j];
        }
    }
}

// ---------------- degree + dinv ----------------
__global__ void deg_count(const int* __restrict__ dst, int* __restrict__ deg) {
    int e = blockIdx.x * blockDim.x + threadIdx.x;
    if (e < EE) atomicAdd(&deg[dst[e]], 1);
}

__global__ void make_dinv(const int* __restrict__ deg, float* __restrict__ dinv) {
    int i = blockIdx.x * blockDim.x + threadIdx.x;
    if (i < NN) dinv[i] = rsqrtf((float)deg[i] + 1.0f);
}

// ---------------- edge scatter: agg[dst] += h[src] * norm ----------------
template <int F>
__global__ void agg_scatter(const float4* __restrict__ h, const int* __restrict__ src,
                            const int* __restrict__ dst, const float* __restrict__ dinv,
                            float* __restrict__ agg) {
    const int LPE = F / 4;  // lanes per edge
    long long t = (long long)blockIdx.x * blockDim.x + threadIdx.x;
    int e = (int)(t / LPE);
    int l = (int)(t % LPE);
    if (e >= EE) return;
    int s = src[e], d = dst[e];
    float nrm = dinv[s] * dinv[d];
    float4 v = h[(size_t)s * LPE + l];
    float* o = agg + (size_t)d * F + (size_t)l * 4;
    atomicAdd(o + 0, v.x * nrm);
    atomicAdd(o + 1, v.y * nrm);
    atomicAdd(o + 2, v.z * nrm);
    atomicAdd(o + 3, v.w * nrm);
}

// ---------------- self-loop + bias (+relu), in-place on agg ----------------
template <int F, bool RELU>
__global__ void node_finish(const float* __restrict__ h, float* __restrict__ agg,
                            const float* __restrict__ dinv, const float* __restrict__ b) {
    long long t = (long long)blockIdx.x * blockDim.x + threadIdx.x;
    if (t >= (long long)NN * F) return;
    int i = (int)(t / F);
    int f = (int)(t % F);
    float di = dinv[i];
    float v = agg[t] + h[t] * di * di + b[f];
    agg[t] = RELU ? fmaxf(v, 0.f) : v;
}

// ---------------- edge MLP: out[e] = relu((hf[s]-hf[d] ++ ev) @ fW1 + fb1) @ fW2 + fb2 ----------------
__global__ __launch_bounds__(256) void edge_mlp(const float* __restrict__ hf,
                                                const int* __restrict__ src,
                                                const int* __restrict__ dst,
                                                const int* __restrict__ ecat,
                                                const float* __restrict__ ev,
                                                const float* __restrict__ emb0,
                                                const float* __restrict__ emb1,
                                                const float* __restrict__ fW1,
                                                const float* __restrict__ fb1,
                                                const float* __restrict__ fW2,
                                                const float* __restrict__ fb2,
                                                float* __restrict__ out) {
    long long t = (long long)blockIdx.x * blockDim.x + threadIdx.x;
    int e = (int)(t >> 5);
    int l = (int)(t & 31);
    if (e >= EE) return;
    int s = src[e], d = dst[e];
    float z0 = 0.f, z1 = 0.f;
    // node2edge features k = l + 32u, u = 0..3  (128 features)
#pragma unroll
    for (int u = 0; u < 4; u++) {
        int k = l + 32 * u;
        float diff = hf[(size_t)s * 128 + k] - hf[(size_t)d * 128 + k];
        z0 += diff * fW1[k * 2 + 0];
        z1 += diff * fW1[k * 2 + 1];
    }
    // edge_val: features 128,129 (lanes 0,1)
    if (l < 2) {
        float v = ev[(size_t)e * 2 + l];
        int k = 128 + l;
        z0 += v * fW1[k * 2 + 0];
        z1 += v * fW1[k * 2 + 1];
    }
    // embeddings: features 130..161 and 162..193
    int c0 = ecat[(size_t)e * 2 + 0];
    int c1 = ecat[(size_t)e * 2 + 1];
    {
        float v = emb0[c0 * 32 + l];
        int k = 130 + l;
        z0 += v * fW1[k * 2 + 0];
        z1 += v * fW1[k * 2 + 1];
    }
    {
        float v = emb1[c1 * 32 + l];
        int k = 162 + l;
        z0 += v * fW1[k * 2 + 0];
        z1 += v * fW1[k * 2 + 1];
    }
    // reduce within the 32-lane group
#pragma unroll
    for (int off = 16; off > 0; off >>= 1) {
        z0 += __shfl_xor(z0, off, 32);
        z1 += __shfl_xor(z1, off, 32);
    }
    if (l == 0) {
        float y0 = fmaxf(z0 + fb1[0], 0.f);
        float y1 = fmaxf(z1 + fb1[1], 0.f);
        out[(size_t)e * 2 + 0] = y0 * fW2[0] + y1 * fW2[2] + fb2[0];
        out[(size_t)e * 2 + 1] = y0 * fW2[1] + y1 * fW2[3] + fb2[1];
    }
}

extern "C" void kernel_launch(void* const* d_in, const int* in_sizes, int n_in,
                              void* d_out, int out_size, void* d_ws, size_t ws_size,
                              hipStream_t stream) {
    const float* x    = (const float*)d_in[0];
    const int*   eidx = (const int*)d_in[1];
    const int*   src  = eidx;
    const int*   dst  = eidx + EE;
    const int*   ecat = (const int*)d_in[2];
    const float* ev   = (const float*)d_in[3];
    const float* W1   = (const float*)d_in[4];
    const float* b1   = (const float*)d_in[5];
    const float* W2   = (const float*)d_in[6];
    const float* b2   = (const float*)d_in[7];
    const float* emb0 = (const float*)d_in[8];
    const float* emb1 = (const float*)d_in[9];
    const float* fW1  = (const float*)d_in[10];
    const float* fb1  = (const float*)d_in[11];
    const float* fW2  = (const float*)d_in[12];
    const float* fb2  = (const float*)d_in[13];
    float* out = (float*)d_out;

    char* ws = (char*)d_ws;
    size_t off = 0;
    int* deg = (int*)(ws + off);        off += (size_t)NN * 4;       // 200000
    off = (off + 255) & ~(size_t)255;
    float* dinv = (float*)(ws + off);   off += (size_t)NN * 4;
    off = (off + 255) & ~(size_t)255;
    float* h1 = (float*)(ws + off);     off += (size_t)NN * HID_F * 4;   // 51.2 MB (later reused as agg2/hf)
    off = (off + 255) & ~(size_t)255;
    float* agg1 = (float*)(ws + off);   off += (size_t)NN * HID_F * 4;   // 51.2 MB (becomes out1 in place)
    off = (off + 255) & ~(size_t)255;
    float* h2 = (float*)(ws + off);     off += (size_t)NN * OUT_F * 4;   // 25.6 MB

    hipMemsetAsync(deg, 0, (size_t)NN * 4, stream);
    hipMemsetAsync(agg1, 0, (size_t)NN * HID_F * 4, stream);

    deg_count<<<(EE + 255) / 256, 256, 0, stream>>>(dst, deg);
    make_dinv<<<(NN + 255) / 256, 256, 0, stream>>>(deg, dinv);

    // layer 1: h1 = x @ W1
    {
        dim3 g(HID_F / 64, (NN + 63) / 64);
        gemm_f32<<<g, 256, 0, stream>>>(x, W1, h1, NN, HID_F, IN_F);
    }
    // agg1 += scatter(h1[src] * norm)
    {
        long long nt = (long long)EE * (HID_F / 4);
        agg_scatter<HID_F><<<(int)((nt + 255) / 256), 256, 0, stream>>>(
            (const float4*)h1, src, dst, dinv, agg1);
    }
    // out1 = relu(agg1 + h1*dinv^2 + b1), in place in agg1
    {
        long long nt = (long long)NN * HID_F;
        node_finish<HID_F, true><<<(int)((nt + 255) / 256), 256, 0, stream>>>(h1, agg1, dinv, b1);
    }
    // layer 2: h2 = out1 @ W2
    {
        dim3 g(OUT_F / 64, (NN + 63) / 64);
        gemm_f32<<<g, 256, 0, stream>>>(agg1, W2, h2, NN, OUT_F, HID_F);
    }
    // agg2 reuses h1 buffer
    float* agg2 = h1;
    hipMemsetAsync(agg2, 0, (size_t)NN * OUT_F * 4, stream);
    {
        long long nt = (long long)EE * (OUT_F / 4);
        agg_scatter<OUT_F><<<(int)((nt + 255) / 256), 256, 0, stream>>>(
            (const float4*)h2, src, dst, dinv, agg2);
    }
    // hf = agg2 + h2*dinv^2 + b2 (no relu), in place in agg2
    {
        long long nt = (long long)NN * OUT_F;
        node_finish<OUT_F, false><<<(int)((nt + 255) / 256), 256, 0, stream>>>(h2, agg2, dinv, b2);
    }
    // edge MLP
    {
        long long nt = (long long)EE * 32;
        edge_mlp<<<(int)((nt + 255) / 256), 256, 0, stream>>>(
            agg2, src, dst, ecat, ev, emb0, emb1, fW1, fb1, fW2, fb2, out);
    }
}

// Round 2
// 811.966 us; speedup vs baseline: 5.5933x; 5.5933x over previous
//
#include <hip/hip_runtime.h>

#define NN 50000
#define EE 800000
#define IN_F 256
#define HID_F 256
#define OUT_F 128

// ---------------- GEMM: C[M,Nc] = (A[M,K] @ B[K,Nc]) * scale[m], row-major f32 ----------------
__global__ __launch_bounds__(256) void gemm_f32(const float* __restrict__ A,
                                                const float* __restrict__ B,
                                                float* __restrict__ C,
                                                const float* __restrict__ scale,
                                                int M, int Nc, int K) {
    const int BM = 64, BN = 64, BK = 32;
    __shared__ float As[BK][BM + 1];
    __shared__ float Bs[BK][BN + 1];
    int bm = blockIdx.y * BM, bn = blockIdx.x * BN;
    int tid = threadIdx.x;
    int tx = tid & 15, ty = tid >> 4;   // 16 x 16
    float acc[4][4] = {};
    for (int k0 = 0; k0 < K; k0 += BK) {
        for (int i = tid; i < BM * BK; i += 256) {
            int m = i >> 5, k = i & 31;
            int gm = bm + m;
            As[k][m] = (gm < M) ? A[(size_t)gm * K + k0 + k] : 0.f;
        }
        for (int i = tid; i < BK * BN; i += 256) {
            int k = i >> 6, n = i & 63;
            Bs[k][n] = B[(size_t)(k0 + k) * Nc + bn + n];
        }
        __syncthreads();
#pragma unroll
        for (int k = 0; k < BK; k++) {
            float a[4], b[4];
#pragma unroll
            for (int u = 0; u < 4; u++) { a[u] = As[k][ty * 4 + u]; b[u] = Bs[k][tx * 4 + u]; }
#pragma unroll
            for (int i2 = 0; i2 < 4; i2++)
#pragma unroll
                for (int j = 0; j < 4; j++) acc[i2][j] += a[i2] * b[j];
        }
        __syncthreads();
    }
#pragma unroll
    for (int i2 = 0; i2 < 4; i2++) {
        int m = bm + ty * 4 + i2;
        if (m < M) {
            float sc = scale ? scale[m] : 1.0f;
#pragma unroll
            for (int j = 0; j < 4; j++)
                C[(size_t)m * Nc + bn + tx * 4 + j] = acc[i2][j] * sc;
        }
    }
}

// ---------------- degree + dinv ----------------
__global__ void deg_count(const int* __restrict__ dst, int* __restrict__ deg) {
    int e = blockIdx.x * blockDim.x + threadIdx.x;
    if (e < EE) atomicAdd(&deg[dst[e]], 1);
}

__global__ void make_dinv(const int* __restrict__ deg, float* __restrict__ dinv) {
    int i = blockIdx.x * blockDim.x + threadIdx.x;
    if (i < NN) dinv[i] = rsqrtf((float)deg[i] + 1.0f);
}

// ---------------- exclusive prefix sum of deg -> rowptr[NN+1] (single block) ----------------
__global__ __launch_bounds__(1024) void scan_rowptr(const int* __restrict__ deg,
                                                    int* __restrict__ rowptr) {
    __shared__ int sdata[1024];
    __shared__ int carry_s;
    int tid = threadIdx.x;
    if (tid == 0) carry_s = 0;
    __syncthreads();
    for (int base = 0; base < NN; base += 1024) {
        int idx = base + tid;
        int v = (idx < NN) ? deg[idx] : 0;
        sdata[tid] = v;
        __syncthreads();
        for (int off = 1; off < 1024; off <<= 1) {
            int t = (tid >= off) ? sdata[tid - off] : 0;
            __syncthreads();
            sdata[tid] += t;
            __syncthreads();
        }
        int incl = sdata[tid];
        if (idx < NN) rowptr[idx] = carry_s + (incl - v);
        __syncthreads();
        if (tid == 1023) carry_s += sdata[1023];
        __syncthreads();
    }
    if (tid == 0) rowptr[NN] = carry_s;
}

// ---------------- CSR bucket fill: edges grouped by dst ----------------
__global__ void fill_csr(const int* __restrict__ src, const int* __restrict__ dst,
                         const int* __restrict__ rowptr, int* __restrict__ cursor,
                         int* __restrict__ csr_src) {
    int e = blockIdx.x * blockDim.x + threadIdx.x;
    if (e >= EE) return;
    int d = dst[e];
    int pos = atomicAdd(&cursor[d], 1);
    csr_src[rowptr[d] + pos] = src[e];
}

// ---------------- CSR gather: out[i] = act((sum_j hs[src_j] + hs[i]) * dinv[i] + b) ----------------
template <int F, bool RELU>
__global__ __launch_bounds__(F) void gather_agg(const float* __restrict__ hs,
                                                const int* __restrict__ rowptr,
                                                const int* __restrict__ csr_src,
                                                const float* __restrict__ dinv,
                                                const float* __restrict__ bias,
                                                float* __restrict__ outp) {
    __shared__ int s_src[64];
    int i = blockIdx.x;
    int f = threadIdx.x;
    int start = rowptr[i], end = rowptr[i + 1];
    float acc = 0.f;
    for (int j0 = start; j0 < end; j0 += 64) {
        int cnt = min(64, end - j0);
        if (f < cnt) s_src[f] = csr_src[j0 + f];
        __syncthreads();
        for (int j = 0; j < cnt; j++) acc += hs[(size_t)s_src[j] * F + f];
        __syncthreads();
    }
    acc = (acc + hs[(size_t)i * F + f]) * dinv[i] + bias[f];
    if (RELU) acc = fmaxf(acc, 0.f);
    outp[(size_t)i * F + f] = acc;
}

// ---------------- edge MLP ----------------
__global__ __launch_bounds__(256) void edge_mlp(const float* __restrict__ hf,
                                                const int* __restrict__ src,
                                                const int* __restrict__ dst,
                                                const int* __restrict__ ecat,
                                                const float* __restrict__ ev,
                                                const float* __restrict__ emb0,
                                                const float* __restrict__ emb1,
                                                const float* __restrict__ fW1,
                                                const float* __restrict__ fb1,
                                                const float* __restrict__ fW2,
                                                const float* __restrict__ fb2,
                                                float* __restrict__ out) {
    long long t = (long long)blockIdx.x * blockDim.x + threadIdx.x;
    int e = (int)(t >> 5);
    int l = (int)(t & 31);
    if (e >= EE) return;
    int s = src[e], d = dst[e];
    float z0 = 0.f, z1 = 0.f;
#pragma unroll
    for (int u = 0; u < 4; u++) {
        int k = l + 32 * u;
        float diff = hf[(size_t)s * 128 + k] - hf[(size_t)d * 128 + k];
        z0 += diff * fW1[k * 2 + 0];
        z1 += diff * fW1[k * 2 + 1];
    }
    if (l < 2) {
        float v = ev[(size_t)e * 2 + l];
        int k = 128 + l;
        z0 += v * fW1[k * 2 + 0];
        z1 += v * fW1[k * 2 + 1];
    }
    int c0 = ecat[(size_t)e * 2 + 0];
    int c1 = ecat[(size_t)e * 2 + 1];
    {
        float v = emb0[c0 * 32 + l];
        int k = 130 + l;
        z0 += v * fW1[k * 2 + 0];
        z1 += v * fW1[k * 2 + 1];
    }
    {
        float v = emb1[c1 * 32 + l];
        int k = 162 + l;
        z0 += v * fW1[k * 2 + 0];
        z1 += v * fW1[k * 2 + 1];
    }
#pragma unroll
    for (int off = 16; off > 0; off >>= 1) {
        z0 += __shfl_xor(z0, off, 32);
        z1 += __shfl_xor(z1, off, 32);
    }
    if (l == 0) {
        float y0 = fmaxf(z0 + fb1[0], 0.f);
        float y1 = fmaxf(z1 + fb1[1], 0.f);
        out[(size_t)e * 2 + 0] = y0 * fW2[0] + y1 * fW2[2] + fb2[0];
        out[(size_t)e * 2 + 1] = y0 * fW2[1] + y1 * fW2[3] + fb2[1];
    }
}

extern "C" void kernel_launch(void* const* d_in, const int* in_sizes, int n_in,
                              void* d_out, int out_size, void* d_ws, size_t ws_size,
                              hipStream_t stream) {
    const float* x    = (const float*)d_in[0];
    const int*   eidx = (const int*)d_in[1];
    const int*   src  = eidx;
    const int*   dst  = eidx + EE;
    const int*   ecat = (const int*)d_in[2];
    const float* ev   = (const float*)d_in[3];
    const float* W1   = (const float*)d_in[4];
    const float* b1   = (const float*)d_in[5];
    const float* W2   = (const float*)d_in[6];
    const float* b2   = (const float*)d_in[7];
    const float* emb0 = (const float*)d_in[8];
    const float* emb1 = (const float*)d_in[9];
    const float* fW1  = (const float*)d_in[10];
    const float* fb1  = (const float*)d_in[11];
    const float* fW2  = (const float*)d_in[12];
    const float* fb2  = (const float*)d_in[13];
    float* out = (float*)d_out;

    char* ws = (char*)d_ws;
    size_t off = 0;
    auto alloc = [&](size_t bytes) {
        void* p = ws + off;
        off = (off + bytes + 255) & ~(size_t)255;
        return p;
    };
    int*   deg     = (int*)alloc((size_t)NN * 4);
    float* dinv    = (float*)alloc((size_t)NN * 4);
    int*   rowptr  = (int*)alloc((size_t)(NN + 1) * 4);
    int*   cursor  = (int*)alloc((size_t)NN * 4);
    int*   csr_src = (int*)alloc((size_t)EE * 4);
    float* hs1     = (float*)alloc((size_t)NN * HID_F * 4);  // 51.2 MB; reused for hs2+hf
    float* out1    = (float*)alloc((size_t)NN * HID_F * 4);  // 51.2 MB
    float* hs2     = hs1;                                    // 25.6 MB (after hs1 dead)
    float* hf      = hs1 + (size_t)NN * OUT_F;               // 25.6 MB

    hipMemsetAsync(deg, 0, (size_t)NN * 4, stream);
    hipMemsetAsync(cursor, 0, (size_t)NN * 4, stream);

    // ---- graph structure (once, reused by both layers) ----
    deg_count<<<(EE + 255) / 256, 256, 0, stream>>>(dst, deg);
    make_dinv<<<(NN + 255) / 256, 256, 0, stream>>>(deg, dinv);
    scan_rowptr<<<1, 1024, 0, stream>>>(deg, rowptr);
    fill_csr<<<(EE + 255) / 256, 256, 0, stream>>>(src, dst, rowptr, cursor, csr_src);

    // ---- layer 1: hs1 = (x @ W1) * dinv ----
    {
        dim3 g(HID_F / 64, (NN + 63) / 64);
        gemm_f32<<<g, 256, 0, stream>>>(x, W1, hs1, dinv, NN, HID_F, IN_F);
    }
    // out1 = relu((gather(hs1) + hs1[i]) * dinv + b1)
    gather_agg<HID_F, true><<<NN, HID_F, 0, stream>>>(hs1, rowptr, csr_src, dinv, b1, out1);

    // ---- layer 2: hs2 = (out1 @ W2) * dinv ----
    {
        dim3 g(OUT_F / 64, (NN + 63) / 64);
        gemm_f32<<<g, 256, 0, stream>>>(out1, W2, hs2, dinv, NN, OUT_F, HID_F);
    }
    // hf = (gather(hs2) + hs2[i]) * dinv + b2
    gather_agg<OUT_F, false><<<NN, OUT_F, 0, stream>>>(hs2, rowptr, csr_src, dinv, b2, hf);

    // ---- edge MLP ----
    {
        long long nt = (long long)EE * 32;
        edge_mlp<<<(int)((nt + 255) / 256), 256, 0, stream>>>(
            hf, src, dst, ecat, ev, emb0, emb1, fW1, fb1, fW2, fb2, out);
    }
}

// Round 3
// 381.881 us; speedup vs baseline: 11.8926x; 2.1262x over previous
//
#include <hip/hip_runtime.h>

#define NN 50000
#define EE 800000
#define IN_F 256
#define HID_F 256
#define OUT_F 128

static __device__ __forceinline__ float4 add4(float4 a, float4 b) {
    return make_float4(a.x + b.x, a.y + b.y, a.z + b.z, a.w + b.w);
}

// ---------------- GEMM1: C[M,256] = (A[M,256] @ B[256,256]) * dinv[m] ----------------
__global__ __launch_bounds__(256) void gemm1(const float* __restrict__ A,
                                             const float* __restrict__ B,
                                             const float* __restrict__ dinv,
                                             float* __restrict__ C, int M) {
    const int BM = 128, BN = 128, BK = 16;
    const int K = 256, Nc = 256;
    __shared__ float As[BK][BM + 4];
    __shared__ float Bs[BK][BN + 4];
    int tid = threadIdx.x;
    int bm = blockIdx.y * BM, bn = blockIdx.x * BN;
    int tx = tid & 15, ty = tid >> 4;
    int aq = tid & 3, arow = tid >> 2;     // A loader: col-quad, row
    int brow = tid >> 5, bcol = (tid & 31) * 4;  // B loader
    float acc[8][8] = {};
    for (int k0 = 0; k0 < K; k0 += BK) {
#pragma unroll
        for (int h = 0; h < 2; ++h) {
            int r = arow + h * 64;
            int gm = bm + r;
            float4 v = make_float4(0.f, 0.f, 0.f, 0.f);
            if (gm < M) v = *(const float4*)&A[(size_t)gm * K + k0 + aq * 4];
            As[aq * 4 + 0][r] = v.x;
            As[aq * 4 + 1][r] = v.y;
            As[aq * 4 + 2][r] = v.z;
            As[aq * 4 + 3][r] = v.w;
        }
#pragma unroll
        for (int h = 0; h < 2; ++h) {
            int r = brow + h * 8;
            float4 v = *(const float4*)&B[(size_t)(k0 + r) * Nc + bn + bcol];
            *(float4*)&Bs[r][bcol] = v;
        }
        __syncthreads();
#pragma unroll
        for (int k = 0; k < BK; ++k) {
            float4 a0 = *(const float4*)&As[k][ty * 8];
            float4 a1 = *(const float4*)&As[k][ty * 8 + 4];
            float4 b0 = *(const float4*)&Bs[k][tx * 8];
            float4 b1 = *(const float4*)&Bs[k][tx * 8 + 4];
            float a[8] = {a0.x, a0.y, a0.z, a0.w, a1.x, a1.y, a1.z, a1.w};
            float b[8] = {b0.x, b0.y, b0.z, b0.w, b1.x, b1.y, b1.z, b1.w};
#pragma unroll
            for (int i = 0; i < 8; ++i)
#pragma unroll
                for (int j = 0; j < 8; ++j) acc[i][j] += a[i] * b[j];
        }
        __syncthreads();
    }
#pragma unroll
    for (int i = 0; i < 8; ++i) {
        int m = bm + ty * 8 + i;
        if (m < M) {
            float sc = dinv[m];
            float4 o0 = make_float4(acc[i][0] * sc, acc[i][1] * sc, acc[i][2] * sc, acc[i][3] * sc);
            float4 o1 = make_float4(acc[i][4] * sc, acc[i][5] * sc, acc[i][6] * sc, acc[i][7] * sc);
            *(float4*)&C[(size_t)m * Nc + bn + tx * 8] = o0;
            *(float4*)&C[(size_t)m * Nc + bn + tx * 8 + 4] = o1;
        }
    }
}

// ---------------- degree + dinv ----------------
__global__ void deg_count(const int* __restrict__ dst, int* __restrict__ deg) {
    int e = blockIdx.x * blockDim.x + threadIdx.x;
    if (e < EE) atomicAdd(&deg[dst[e]], 1);
}

__global__ void make_dinv(const int* __restrict__ deg, float* __restrict__ dinv) {
    int i = blockIdx.x * blockDim.x + threadIdx.x;
    if (i < NN) dinv[i] = rsqrtf((float)deg[i] + 1.0f);
}

// ---------------- exclusive prefix sum (shfl-based, single block) ----------------
__global__ __launch_bounds__(1024) void scan_rowptr(const int* __restrict__ deg,
                                                    int* __restrict__ rowptr) {
    __shared__ int wsum[16];
    __shared__ int carry_s;
    int tid = threadIdx.x, lane = tid & 63, w = tid >> 6;
    if (tid == 0) carry_s = 0;
    __syncthreads();
    for (int base = 0; base < NN; base += 1024) {
        int idx = base + tid;
        int v = (idx < NN) ? deg[idx] : 0;
        int x = v;
#pragma unroll
        for (int off = 1; off < 64; off <<= 1) {
            int t = __shfl_up(x, off, 64);
            if (lane >= off) x += t;
        }
        if (lane == 63) wsum[w] = x;
        __syncthreads();                       // A: wsum ready, carry_s stable
        int carry = carry_s;
        if (w == 0) {
            int s = (lane < 16) ? wsum[lane] : 0;
#pragma unroll
            for (int off = 1; off < 16; off <<= 1) {
                int t = __shfl_up(s, off, 64);
                if (lane >= off) s += t;
            }
            if (lane < 16) wsum[lane] = s;     // inclusive over waves
        }
        __syncthreads();                       // B: wave-prefix ready
        int wpre = (w == 0) ? 0 : wsum[w - 1];
        if (idx < NN) rowptr[idx] = carry + wpre + (x - v);
        if (tid == 0) carry_s = carry + wsum[15];
        __syncthreads();                       // C: protect wsum/carry_s
    }
    if (threadIdx.x == 0) rowptr[NN] = carry_s;
}

// ---------------- CSR bucket fill ----------------
__global__ void fill_csr(const int* __restrict__ src, const int* __restrict__ dst,
                         const int* __restrict__ rowptr, int* __restrict__ cursor,
                         int* __restrict__ csr_src) {
    int e = blockIdx.x * blockDim.x + threadIdx.x;
    if (e >= EE) return;
    int d = dst[e];
    int pos = atomicAdd(&cursor[d], 1);
    csr_src[rowptr[d] + pos] = src[e];
}

// ---------------- tiny precompute: Wf^T [2][256], t0/t1 [20] float2 ----------------
__global__ __launch_bounds__(256) void precompute(const float* __restrict__ W2,
                                                  const float* __restrict__ fW1,
                                                  const float* __restrict__ emb0,
                                                  const float* __restrict__ emb1,
                                                  float* __restrict__ Wft,
                                                  float2* __restrict__ t0,
                                                  float2* __restrict__ t1) {
    int k = threadIdx.x;
    float s0 = 0.f, s1 = 0.f;
    for (int m = 0; m < OUT_F; ++m) {
        float w = W2[(size_t)k * OUT_F + m];
        s0 += w * fW1[m * 2 + 0];
        s1 += w * fW1[m * 2 + 1];
    }
    Wft[k] = s0;
    Wft[256 + k] = s1;
    if (k < 20) {
        float a0 = 0.f, a1 = 0.f, b0 = 0.f, b1v = 0.f;
        for (int u = 0; u < 32; ++u) {
            float e0 = emb0[k * 32 + u], e1 = emb1[k * 32 + u];
            a0 += e0 * fW1[(130 + u) * 2 + 0];
            a1 += e0 * fW1[(130 + u) * 2 + 1];
            b0 += e1 * fW1[(162 + u) * 2 + 0];
            b1v += e1 * fW1[(162 + u) * 2 + 1];
        }
        t0[k] = make_float2(a0, a1);
        t1[k] = make_float2(b0, b1v);
    }
}

// ---------------- fused gather + relu + 2-col projection: q[i] = dinv*(relu(...) @ Wf) ----------------
__global__ __launch_bounds__(256) void gather_project(const float4* __restrict__ hs4,
                                                      const int* __restrict__ rowptr,
                                                      const int* __restrict__ csr_src,
                                                      const float* __restrict__ dinv,
                                                      const float4* __restrict__ b1_4,
                                                      const float4* __restrict__ Wft4,
                                                      float2* __restrict__ q) {
    int i = blockIdx.x * 4 + (threadIdx.x >> 6);
    int l = threadIdx.x & 63;
    if (i >= NN) return;
    int start = rowptr[i], end = rowptr[i + 1];
    float4 acc = make_float4(0.f, 0.f, 0.f, 0.f);
    int j = start;
    for (; j + 3 < end; j += 4) {
        int s0 = csr_src[j], s1 = csr_src[j + 1], s2 = csr_src[j + 2], s3 = csr_src[j + 3];
        float4 v0 = hs4[(size_t)s0 * 64 + l];
        float4 v1 = hs4[(size_t)s1 * 64 + l];
        float4 v2 = hs4[(size_t)s2 * 64 + l];
        float4 v3 = hs4[(size_t)s3 * 64 + l];
        acc = add4(add4(add4(add4(acc, v0), v1), v2), v3);
    }
    for (; j < end; ++j) {
        acc = add4(acc, hs4[(size_t)csr_src[j] * 64 + l]);
    }
    float di = dinv[i];
    float4 self = hs4[(size_t)i * 64 + l];
    float4 bb = b1_4[l];
    float4 o;
    o.x = fmaxf((acc.x + self.x) * di + bb.x, 0.f);
    o.y = fmaxf((acc.y + self.y) * di + bb.y, 0.f);
    o.z = fmaxf((acc.z + self.z) * di + bb.z, 0.f);
    o.w = fmaxf((acc.w + self.w) * di + bb.w, 0.f);
    float4 w0 = Wft4[l], w1 = Wft4[64 + l];
    float q0 = o.x * w0.x + o.y * w0.y + o.z * w0.z + o.w * w0.w;
    float q1 = o.x * w1.x + o.y * w1.y + o.z * w1.z + o.w * w1.w;
#pragma unroll
    for (int off = 32; off > 0; off >>= 1) {
        q0 += __shfl_xor(q0, off, 64);
        q1 += __shfl_xor(q1, off, 64);
    }
    if (l == 0) q[i] = make_float2(q0 * di, q1 * di);
}

// ---------------- gn[i] = (sum_j q[j] + q[i]) * dinv[i]  (b2 term cancels in edge diff) ----------------
__global__ __launch_bounds__(256) void gather_gn(const float2* __restrict__ q,
                                                 const int* __restrict__ rowptr,
                                                 const int* __restrict__ csr_src,
                                                 const float* __restrict__ dinv,
                                                 float2* __restrict__ gn) {
    int i = blockIdx.x * blockDim.x + threadIdx.x;
    if (i >= NN) return;
    int start = rowptr[i], end = rowptr[i + 1];
    float a0 = 0.f, a1 = 0.f;
    for (int j = start; j < end; ++j) {
        float2 v = q[csr_src[j]];
        a0 += v.x;
        a1 += v.y;
    }
    float2 self = q[i];
    float di = dinv[i];
    gn[i] = make_float2((a0 + self.x) * di, (a1 + self.y) * di);
}

// ---------------- final edge kernel ----------------
__global__ __launch_bounds__(256) void edge_out(const float2* __restrict__ gn,
                                                const int* __restrict__ src,
                                                const int* __restrict__ dst,
                                                const int2* __restrict__ ecat,
                                                const float2* __restrict__ ev,
                                                const float* __restrict__ fW1,
                                                const float2* __restrict__ t0,
                                                const float2* __restrict__ t1,
                                                const float* __restrict__ fb1,
                                                const float* __restrict__ fW2,
                                                const float* __restrict__ fb2,
                                                float2* __restrict__ out) {
    int e = blockIdx.x * blockDim.x + threadIdx.x;
    if (e >= EE) return;
    int s = src[e], d = dst[e];
    float2 gs = gn[s], gd = gn[d];
    int2 c = ecat[e];
    float2 v = ev[e];
    float2 e0 = t0[c.x], e1 = t1[c.y];
    float z0 = gs.x - gd.x + v.x * fW1[128 * 2 + 0] + v.y * fW1[129 * 2 + 0] + e0.x + e1.x;
    float z1 = gs.y - gd.y + v.x * fW1[128 * 2 + 1] + v.y * fW1[129 * 2 + 1] + e0.y + e1.y;
    float y0 = fmaxf(z0 + fb1[0], 0.f);
    float y1 = fmaxf(z1 + fb1[1], 0.f);
    out[e] = make_float2(y0 * fW2[0] + y1 * fW2[2] + fb2[0],
                         y0 * fW2[1] + y1 * fW2[3] + fb2[1]);
}

extern "C" void kernel_launch(void* const* d_in, const int* in_sizes, int n_in,
                              void* d_out, int out_size, void* d_ws, size_t ws_size,
                              hipStream_t stream) {
    const float* x    = (const float*)d_in[0];
    const int*   eidx = (const int*)d_in[1];
    const int*   src  = eidx;
    const int*   dst  = eidx + EE;
    const int*   ecat = (const int*)d_in[2];
    const float* ev   = (const float*)d_in[3];
    const float* W1   = (const float*)d_in[4];
    const float* b1   = (const float*)d_in[5];
    const float* W2   = (const float*)d_in[6];
    // b2 (d_in[7]) cancels in gn[s]-gn[d]; unused.
    const float* emb0 = (const float*)d_in[8];
    const float* emb1 = (const float*)d_in[9];
    const float* fW1  = (const float*)d_in[10];
    const float* fb1  = (const float*)d_in[11];
    const float* fW2  = (const float*)d_in[12];
    const float* fb2  = (const float*)d_in[13];
    float* out = (float*)d_out;

    char* ws = (char*)d_ws;
    size_t off = 0;
    auto alloc = [&](size_t bytes) {
        void* p = ws + off;
        off = (off + bytes + 255) & ~(size_t)255;
        return p;
    };
    int*    deg     = (int*)alloc((size_t)NN * 4);
    float*  dinv    = (float*)alloc((size_t)NN * 4);
    int*    rowptr  = (int*)alloc((size_t)(NN + 1) * 4);
    int*    cursor  = (int*)alloc((size_t)NN * 4);
    int*    csr_src = (int*)alloc((size_t)EE * 4);
    float*  h1s     = (float*)alloc((size_t)NN * HID_F * 4);  // 51.2 MB
    float2* q       = (float2*)alloc((size_t)NN * 8);
    float2* gn      = (float2*)alloc((size_t)NN * 8);
    float*  Wft     = (float*)alloc(512 * 4);
    float2* t0      = (float2*)alloc(20 * 8);
    float2* t1      = (float2*)alloc(20 * 8);

    hipMemsetAsync(deg, 0, (size_t)NN * 4, stream);
    hipMemsetAsync(cursor, 0, (size_t)NN * 4, stream);

    // graph structure
    deg_count<<<(EE + 255) / 256, 256, 0, stream>>>(dst, deg);
    make_dinv<<<(NN + 255) / 256, 256, 0, stream>>>(deg, dinv);
    scan_rowptr<<<1, 1024, 0, stream>>>(deg, rowptr);
    fill_csr<<<(EE + 255) / 256, 256, 0, stream>>>(src, dst, rowptr, cursor, csr_src);

    // tiny projections
    precompute<<<1, 256, 0, stream>>>(W2, fW1, emb0, emb1, Wft, t0, t1);

    // layer 1 GEMM: h1s = (x @ W1) * dinv
    {
        dim3 g(HID_F / 128, (NN + 127) / 128);
        gemm1<<<g, 256, 0, stream>>>(x, W1, dinv, h1s, NN);
    }
    // fused gather + relu + project -> q [N,2]
    gather_project<<<(NN + 3) / 4, 256, 0, stream>>>(
        (const float4*)h1s, rowptr, csr_src, dinv, (const float4*)b1,
        (const float4*)Wft, q);
    // gn [N,2]
    gather_gn<<<(NN + 255) / 256, 256, 0, stream>>>(q, rowptr, csr_src, dinv, gn);
    // edges
    edge_out<<<(EE + 255) / 256, 256, 0, stream>>>(
        gn, src, dst, (const int2*)ecat, (const float2*)ev,
        fW1, t0, t1, fb1, fW2, fb2, (float2*)out);
}

// Round 4
// 273.415 us; speedup vs baseline: 16.6105x; 1.3967x over previous
//
#include <hip/hip_runtime.h>

#define NN 50000
#define EE 800000
#define IN_F 256
#define HID_F 256
#define OUT_F 128
#define NB ((NN + 1023) / 1024)   // 49 scan blocks

typedef _Float16 half8v __attribute__((ext_vector_type(8)));

// ---------------- GEMM1: C[M,256] = fp16((A[M,256] @ B[256,256]) * dinv[m]) ----------------
__global__ __launch_bounds__(256) void gemm1(const float* __restrict__ A,
                                             const float* __restrict__ B,
                                             const float* __restrict__ dinv,
                                             _Float16* __restrict__ C, int M) {
    const int BM = 128, BN = 128, BK = 16;
    const int K = 256, Nc = 256;
    __shared__ float As[BK][BM + 4];
    __shared__ float Bs[BK][BN + 4];
    int tid = threadIdx.x;
    int bm = blockIdx.y * BM, bn = blockIdx.x * BN;
    int tx = tid & 15, ty = tid >> 4;
    int aq = tid & 3, arow = tid >> 2;
    int brow = tid >> 5, bcol = (tid & 31) * 4;
    float acc[8][8] = {};
    for (int k0 = 0; k0 < K; k0 += BK) {
#pragma unroll
        for (int h = 0; h < 2; ++h) {
            int r = arow + h * 64;
            int gm = bm + r;
            float4 v = make_float4(0.f, 0.f, 0.f, 0.f);
            if (gm < M) v = *(const float4*)&A[(size_t)gm * K + k0 + aq * 4];
            As[aq * 4 + 0][r] = v.x;
            As[aq * 4 + 1][r] = v.y;
            As[aq * 4 + 2][r] = v.z;
            As[aq * 4 + 3][r] = v.w;
        }
#pragma unroll
        for (int h = 0; h < 2; ++h) {
            int r = brow + h * 8;
            float4 v = *(const float4*)&B[(size_t)(k0 + r) * Nc + bn + bcol];
            *(float4*)&Bs[r][bcol] = v;
        }
        __syncthreads();
#pragma unroll
        for (int k = 0; k < BK; ++k) {
            float4 a0 = *(const float4*)&As[k][ty * 8];
            float4 a1 = *(const float4*)&As[k][ty * 8 + 4];
            float4 b0 = *(const float4*)&Bs[k][tx * 8];
            float4 b1 = *(const float4*)&Bs[k][tx * 8 + 4];
            float a[8] = {a0.x, a0.y, a0.z, a0.w, a1.x, a1.y, a1.z, a1.w};
            float b[8] = {b0.x, b0.y, b0.z, b0.w, b1.x, b1.y, b1.z, b1.w};
#pragma unroll
            for (int i = 0; i < 8; ++i)
#pragma unroll
                for (int j = 0; j < 8; ++j) acc[i][j] += a[i] * b[j];
        }
        __syncthreads();
    }
#pragma unroll
    for (int i = 0; i < 8; ++i) {
        int m = bm + ty * 8 + i;
        if (m < M) {
            float sc = dinv[m];
            half8v o;
#pragma unroll
            for (int j = 0; j < 8; ++j) o[j] = (_Float16)(acc[i][j] * sc);
            *(half8v*)&C[(size_t)m * Nc + bn + tx * 8] = o;
        }
    }
}

// ---------------- degree + dinv ----------------
__global__ void deg_count(const int* __restrict__ dst, int* __restrict__ deg) {
    int e = blockIdx.x * blockDim.x + threadIdx.x;
    if (e < EE) atomicAdd(&deg[dst[e]], 1);
}

__global__ void make_dinv(const int* __restrict__ deg, float* __restrict__ dinv) {
    int i = blockIdx.x * blockDim.x + threadIdx.x;
    if (i < NN) dinv[i] = rsqrtf((float)deg[i] + 1.0f);
}

// ---------------- 3-kernel parallel scan: deg -> rowptr ----------------
__global__ __launch_bounds__(1024) void scan_partial(const int* __restrict__ deg,
                                                     int* __restrict__ rowptr,
                                                     int* __restrict__ bsum) {
    __shared__ int wsum[16];
    int tid = threadIdx.x, lane = tid & 63, w = tid >> 6;
    int idx = blockIdx.x * 1024 + tid;
    int v = (idx < NN) ? deg[idx] : 0;
    int x = v;
#pragma unroll
    for (int off = 1; off < 64; off <<= 1) {
        int t = __shfl_up(x, off, 64);
        if (lane >= off) x += t;
    }
    if (lane == 63) wsum[w] = x;
    __syncthreads();
    if (w == 0) {
        int s = (lane < 16) ? wsum[lane] : 0;
#pragma unroll
        for (int off = 1; off < 16; off <<= 1) {
            int t = __shfl_up(s, off, 64);
            if (lane >= off) s += t;
        }
        if (lane < 16) wsum[lane] = s;
    }
    __syncthreads();
    int wpre = (w == 0) ? 0 : wsum[w - 1];
    if (idx < NN) rowptr[idx] = wpre + (x - v);     // exclusive within block
    if (tid == 0) bsum[blockIdx.x] = wsum[15];      // block total
}

__global__ __launch_bounds__(64) void scan_bsum(int* __restrict__ bsum,
                                                int* __restrict__ rowptr) {
    int l = threadIdx.x;
    int v = (l < NB) ? bsum[l] : 0;
    int x = v;
#pragma unroll
    for (int off = 1; off < 64; off <<= 1) {
        int t = __shfl_up(x, off, 64);
        if (l >= off) x += t;
    }
    if (l < NB) bsum[l] = x - v;                    // exclusive over blocks
    if (l == NB - 1) rowptr[NN] = x;                // grand total = EE
}

__global__ void scan_add(int* __restrict__ rowptr, const int* __restrict__ bsum) {
    int idx = blockIdx.x * blockDim.x + threadIdx.x;
    if (idx < NN) rowptr[idx] += bsum[idx >> 10];
}

// ---------------- CSR bucket fill ----------------
__global__ void fill_csr(const int* __restrict__ src, const int* __restrict__ dst,
                         const int* __restrict__ rowptr, int* __restrict__ cursor,
                         int* __restrict__ csr_src) {
    int e = blockIdx.x * blockDim.x + threadIdx.x;
    if (e >= EE) return;
    int d = dst[e];
    int pos = atomicAdd(&cursor[d], 1);
    csr_src[rowptr[d] + pos] = src[e];
}

// ---------------- tiny precompute: Wf^T [2][256], t0/t1 [20] float2 ----------------
__global__ __launch_bounds__(256) void precompute(const float* __restrict__ W2,
                                                  const float* __restrict__ fW1,
                                                  const float* __restrict__ emb0,
                                                  const float* __restrict__ emb1,
                                                  float* __restrict__ Wft,
                                                  float2* __restrict__ t0,
                                                  float2* __restrict__ t1) {
    int k = threadIdx.x;
    float s0 = 0.f, s1 = 0.f;
    for (int m = 0; m < OUT_F; ++m) {
        float w = W2[(size_t)k * OUT_F + m];
        s0 += w * fW1[m * 2 + 0];
        s1 += w * fW1[m * 2 + 1];
    }
    Wft[k] = s0;
    Wft[256 + k] = s1;
    if (k < 20) {
        float a0 = 0.f, a1 = 0.f, b0 = 0.f, b1v = 0.f;
        for (int u = 0; u < 32; ++u) {
            float e0 = emb0[k * 32 + u], e1 = emb1[k * 32 + u];
            a0 += e0 * fW1[(130 + u) * 2 + 0];
            a1 += e0 * fW1[(130 + u) * 2 + 1];
            b0 += e1 * fW1[(162 + u) * 2 + 0];
            b1v += e1 * fW1[(162 + u) * 2 + 1];
        }
        t0[k] = make_float2(a0, a1);
        t1[k] = make_float2(b0, b1v);
    }
}

// ---------------- fused gather (fp16 rows) + relu + 2-col projection ----------------
// one wave per node; lanes split as (le = lane>>5) edge-slot, (lf = lane&31) feature-octet
__global__ __launch_bounds__(256) void gather_project(const _Float16* __restrict__ hs,
                                                      const int* __restrict__ rowptr,
                                                      const int* __restrict__ csr_src,
                                                      const float* __restrict__ dinv,
                                                      const float* __restrict__ b1,
                                                      const float* __restrict__ Wft,
                                                      float2* __restrict__ q) {
    int i = blockIdx.x * 4 + (threadIdx.x >> 6);
    int l = threadIdx.x & 63;
    int lf = l & 31, le = l >> 5;
    if (i >= NN) return;
    int start = rowptr[i], end = rowptr[i + 1];
    float acc[8] = {};
    int j = start;
    for (; j + 7 < end; j += 8) {
        int s0 = csr_src[j + 0 + le];
        int s1 = csr_src[j + 2 + le];
        int s2 = csr_src[j + 4 + le];
        int s3 = csr_src[j + 6 + le];
        half8v v0 = *(const half8v*)(hs + (size_t)s0 * 256 + lf * 8);
        half8v v1 = *(const half8v*)(hs + (size_t)s1 * 256 + lf * 8);
        half8v v2 = *(const half8v*)(hs + (size_t)s2 * 256 + lf * 8);
        half8v v3 = *(const half8v*)(hs + (size_t)s3 * 256 + lf * 8);
#pragma unroll
        for (int u = 0; u < 8; ++u)
            acc[u] += ((float)v0[u] + (float)v1[u]) + ((float)v2[u] + (float)v3[u]);
    }
    for (; j + le < end; j += 2) {
        int s = csr_src[j + le];
        half8v v = *(const half8v*)(hs + (size_t)s * 256 + lf * 8);
#pragma unroll
        for (int u = 0; u < 8; ++u) acc[u] += (float)v[u];
    }
    // combine the two edge-slots feature-wise
#pragma unroll
    for (int u = 0; u < 8; ++u) acc[u] += __shfl_xor(acc[u], 32, 64);
    float di = dinv[i];
    half8v sv = *(const half8v*)(hs + (size_t)i * 256 + lf * 8);
    float q0 = 0.f, q1 = 0.f;
#pragma unroll
    for (int u = 0; u < 8; ++u) {
        float o = fmaxf((acc[u] + (float)sv[u]) * di + b1[lf * 8 + u], 0.f);
        q0 += o * Wft[lf * 8 + u];
        q1 += o * Wft[256 + lf * 8 + u];
    }
#pragma unroll
    for (int off = 16; off > 0; off >>= 1) {
        q0 += __shfl_xor(q0, off, 64);
        q1 += __shfl_xor(q1, off, 64);
    }
    if (l == 0) q[i] = make_float2(q0 * di, q1 * di);
}

// ---------------- gn[i] = (sum_j q[j] + q[i]) * dinv[i] ----------------
__global__ __launch_bounds__(256) void gather_gn(const float2* __restrict__ q,
                                                 const int* __restrict__ rowptr,
                                                 const int* __restrict__ csr_src,
                                                 const float* __restrict__ dinv,
                                                 float2* __restrict__ gn) {
    int i = blockIdx.x * blockDim.x + threadIdx.x;
    if (i >= NN) return;
    int start = rowptr[i], end = rowptr[i + 1];
    float a0 = 0.f, a1 = 0.f;
    for (int j = start; j < end; ++j) {
        float2 v = q[csr_src[j]];
        a0 += v.x;
        a1 += v.y;
    }
    float2 self = q[i];
    float di = dinv[i];
    gn[i] = make_float2((a0 + self.x) * di, (a1 + self.y) * di);
}

// ---------------- final edge kernel ----------------
__global__ __launch_bounds__(256) void edge_out(const float2* __restrict__ gn,
                                                const int* __restrict__ src,
                                                const int* __restrict__ dst,
                                                const int2* __restrict__ ecat,
                                                const float2* __restrict__ ev,
                                                const float* __restrict__ fW1,
                                                const float2* __restrict__ t0,
                                                const float2* __restrict__ t1,
                                                const float* __restrict__ fb1,
                                                const float* __restrict__ fW2,
                                                const float* __restrict__ fb2,
                                                float2* __restrict__ out) {
    int e = blockIdx.x * blockDim.x + threadIdx.x;
    if (e >= EE) return;
    int s = src[e], d = dst[e];
    float2 gs = gn[s], gd = gn[d];
    int2 c = ecat[e];
    float2 v = ev[e];
    float2 e0 = t0[c.x], e1 = t1[c.y];
    float z0 = gs.x - gd.x + v.x * fW1[128 * 2 + 0] + v.y * fW1[129 * 2 + 0] + e0.x + e1.x;
    float z1 = gs.y - gd.y + v.x * fW1[128 * 2 + 1] + v.y * fW1[129 * 2 + 1] + e0.y + e1.y;
    float y0 = fmaxf(z0 + fb1[0], 0.f);
    float y1 = fmaxf(z1 + fb1[1], 0.f);
    out[e] = make_float2(y0 * fW2[0] + y1 * fW2[2] + fb2[0],
                         y0 * fW2[1] + y1 * fW2[3] + fb2[1]);
}

extern "C" void kernel_launch(void* const* d_in, const int* in_sizes, int n_in,
                              void* d_out, int out_size, void* d_ws, size_t ws_size,
                              hipStream_t stream) {
    const float* x    = (const float*)d_in[0];
    const int*   eidx = (const int*)d_in[1];
    const int*   src  = eidx;
    const int*   dst  = eidx + EE;
    const int*   ecat = (const int*)d_in[2];
    const float* ev   = (const float*)d_in[3];
    const float* W1   = (const float*)d_in[4];
    const float* b1   = (const float*)d_in[5];
    const float* W2   = (const float*)d_in[6];
    // b2 (d_in[7]) cancels in gn[s]-gn[d]; unused.
    const float* emb0 = (const float*)d_in[8];
    const float* emb1 = (const float*)d_in[9];
    const float* fW1  = (const float*)d_in[10];
    const float* fb1  = (const float*)d_in[11];
    const float* fW2  = (const float*)d_in[12];
    const float* fb2  = (const float*)d_in[13];
    float* out = (float*)d_out;

    char* ws = (char*)d_ws;
    size_t off = 0;
    auto alloc = [&](size_t bytes) {
        void* p = ws + off;
        off = (off + bytes + 255) & ~(size_t)255;
        return p;
    };
    int*      deg     = (int*)alloc((size_t)NN * 4);
    float*    dinv    = (float*)alloc((size_t)NN * 4);
    int*      rowptr  = (int*)alloc((size_t)(NN + 1) * 4);
    int*      cursor  = (int*)alloc((size_t)NN * 4);
    int*      bsum    = (int*)alloc((size_t)NB * 4);
    int*      csr_src = (int*)alloc((size_t)EE * 4);
    _Float16* h1s     = (_Float16*)alloc((size_t)NN * HID_F * 2);  // 25.6 MB fp16
    float2*   q       = (float2*)alloc((size_t)NN * 8);
    float2*   gn      = (float2*)alloc((size_t)NN * 8);
    float*    Wft     = (float*)alloc(512 * 4);
    float2*   t0      = (float2*)alloc(20 * 8);
    float2*   t1      = (float2*)alloc(20 * 8);

    hipMemsetAsync(deg, 0, (size_t)NN * 4, stream);
    hipMemsetAsync(cursor, 0, (size_t)NN * 4, stream);

    // graph structure
    deg_count<<<(EE + 255) / 256, 256, 0, stream>>>(dst, deg);
    make_dinv<<<(NN + 255) / 256, 256, 0, stream>>>(deg, dinv);
    scan_partial<<<NB, 1024, 0, stream>>>(deg, rowptr, bsum);
    scan_bsum<<<1, 64, 0, stream>>>(bsum, rowptr);
    scan_add<<<(NN + 255) / 256, 256, 0, stream>>>(rowptr, bsum);
    fill_csr<<<(EE + 255) / 256, 256, 0, stream>>>(src, dst, rowptr, cursor, csr_src);

    // tiny projections
    precompute<<<1, 256, 0, stream>>>(W2, fW1, emb0, emb1, Wft, t0, t1);

    // layer 1 GEMM: h1s = fp16((x @ W1) * dinv)
    {
        dim3 g(HID_F / 128, (NN + 127) / 128);
        gemm1<<<g, 256, 0, stream>>>(x, W1, dinv, h1s, NN);
    }
    // fused gather + relu + project -> q [N,2]
    gather_project<<<(NN + 3) / 4, 256, 0, stream>>>(
        h1s, rowptr, csr_src, dinv, b1, Wft, q);
    // gn [N,2]
    gather_gn<<<(NN + 255) / 256, 256, 0, stream>>>(q, rowptr, csr_src, dinv, gn);
    // edges
    edge_out<<<(EE + 255) / 256, 256, 0, stream>>>(
        gn, src, dst, (const int2*)ecat, (const float2*)ev,
        fW1, t0, t1, fb1, fW2, fb2, (float2*)out);
}

// Round 5
// 222.235 us; speedup vs baseline: 20.4359x; 1.2303x over previous
//
#include <hip/hip_runtime.h>

#define NN 50000
#define EE 800000
#define IN_F 256
#define HID_F 256
#define OUT_F 128
#define NB ((NN + 1023) / 1024)   // 49 scan blocks

typedef _Float16 half8v __attribute__((ext_vector_type(8)));
typedef _Float16 half4v __attribute__((ext_vector_type(4)));
typedef float f32x4 __attribute__((ext_vector_type(4)));

// ---------------- MFMA fp16 GEMM: C[M,256] = fp16((A[M,256] @ B[256,256]) * dinv[m]) ----------------
// 128x128 tile, BK=32, 4 waves of 64x64, mfma_f32_16x16x32_f16
__global__ __launch_bounds__(256) void gemm1_mfma(const float* __restrict__ A,
                                                  const float* __restrict__ B,
                                                  const float* __restrict__ dinv,
                                                  _Float16* __restrict__ C, int M) {
    const int BM = 128, BK = 32;
    __shared__ _Float16 Ah[BM][BK + 8];   // row stride 80 B (16B-aligned)
    __shared__ _Float16 Bh[128][BK + 8];  // Bh[n][k] (B^T tile)
    int tid = threadIdx.x;
    int bm = blockIdx.y * BM, bn = blockIdx.x * 128;
    int w = tid >> 6, l = tid & 63;
    int wr = w >> 1, wc = w & 1;          // wave -> 64x64 sub-tile
    int lr = l & 15, lg = l >> 4;
    f32x4 acc[4][4] = {};

    for (int k0 = 0; k0 < 256; k0 += BK) {
        // stage A: rows bm..bm+127, k0..k0+31 (f32 -> fp16). 1024 float4, 4/thread.
#pragma unroll
        for (int i = 0; i < 4; ++i) {
            int idx = tid + i * 256;
            int r = idx >> 3, oc = idx & 7;        // 8 float4 per row
            int gm = bm + r;
            float4 v = make_float4(0.f, 0.f, 0.f, 0.f);
            if (gm < M) v = *(const float4*)&A[(size_t)gm * 256 + k0 + oc * 4];
            half4v h;
            h[0] = (_Float16)v.x; h[1] = (_Float16)v.y;
            h[2] = (_Float16)v.z; h[3] = (_Float16)v.w;
            *(half4v*)&Ah[r][oc * 4] = h;
        }
        // stage B^T: Bh[n][k] from B[k][bn+n]. thread -> (n, kq): 4 strided f32 loads.
#pragma unroll
        for (int i = 0; i < 4; ++i) {
            int idx = tid + i * 256;
            int n = idx & 127, kq = idx >> 7;      // kq in 0..7 over the 4 iters
            half4v h;
#pragma unroll
            for (int u = 0; u < 4; ++u)
                h[u] = (_Float16)B[(size_t)(k0 + kq * 4 + u) * 256 + bn + n];
            *(half4v*)&Bh[n][kq * 4] = h;
        }
        __syncthreads();
        half8v a[4], b[4];
#pragma unroll
        for (int mf = 0; mf < 4; ++mf)
            a[mf] = *(const half8v*)&Ah[wr * 64 + mf * 16 + lr][lg * 8];
#pragma unroll
        for (int nf = 0; nf < 4; ++nf)
            b[nf] = *(const half8v*)&Bh[wc * 64 + nf * 16 + lr][lg * 8];
#pragma unroll
        for (int mf = 0; mf < 4; ++mf)
#pragma unroll
            for (int nf = 0; nf < 4; ++nf)
                acc[mf][nf] = __builtin_amdgcn_mfma_f32_16x16x32_f16(a[mf], b[nf], acc[mf][nf], 0, 0, 0);
        __syncthreads();
    }
    // epilogue: D row = (lane>>4)*4 + reg, col = lane&15 (m89-verified layout)
#pragma unroll
    for (int mf = 0; mf < 4; ++mf) {
#pragma unroll
        for (int reg = 0; reg < 4; ++reg) {
            int gr = bm + wr * 64 + mf * 16 + lg * 4 + reg;
            if (gr < M) {
                float sc = dinv[gr];
#pragma unroll
                for (int nf = 0; nf < 4; ++nf)
                    C[(size_t)gr * 256 + bn + wc * 64 + nf * 16 + lr] =
                        (_Float16)(acc[mf][nf][reg] * sc);
            }
        }
    }
}

// ---------------- degree + dinv ----------------
__global__ void deg_count(const int* __restrict__ dst, int* __restrict__ deg) {
    int e = blockIdx.x * blockDim.x + threadIdx.x;
    if (e < EE) atomicAdd(&deg[dst[e]], 1);
}

__global__ void make_dinv(const int* __restrict__ deg, float* __restrict__ dinv) {
    int i = blockIdx.x * blockDim.x + threadIdx.x;
    if (i < NN) dinv[i] = rsqrtf((float)deg[i] + 1.0f);
}

// ---------------- 3-kernel parallel scan: deg -> rowptr ----------------
__global__ __launch_bounds__(1024) void scan_partial(const int* __restrict__ deg,
                                                     int* __restrict__ rowptr,
                                                     int* __restrict__ bsum) {
    __shared__ int wsum[16];
    int tid = threadIdx.x, lane = tid & 63, w = tid >> 6;
    int idx = blockIdx.x * 1024 + tid;
    int v = (idx < NN) ? deg[idx] : 0;
    int x = v;
#pragma unroll
    for (int off = 1; off < 64; off <<= 1) {
        int t = __shfl_up(x, off, 64);
        if (lane >= off) x += t;
    }
    if (lane == 63) wsum[w] = x;
    __syncthreads();
    if (w == 0) {
        int s = (lane < 16) ? wsum[lane] : 0;
#pragma unroll
        for (int off = 1; off < 16; off <<= 1) {
            int t = __shfl_up(s, off, 64);
            if (lane >= off) s += t;
        }
        if (lane < 16) wsum[lane] = s;
    }
    __syncthreads();
    int wpre = (w == 0) ? 0 : wsum[w - 1];
    if (idx < NN) rowptr[idx] = wpre + (x - v);     // exclusive within block
    if (tid == 0) bsum[blockIdx.x] = wsum[15];      // block total
}

__global__ __launch_bounds__(64) void scan_bsum(int* __restrict__ bsum,
                                                int* __restrict__ rowptr) {
    int l = threadIdx.x;
    int v = (l < NB) ? bsum[l] : 0;
    int x = v;
#pragma unroll
    for (int off = 1; off < 64; off <<= 1) {
        int t = __shfl_up(x, off, 64);
        if (l >= off) x += t;
    }
    if (l < NB) bsum[l] = x - v;                    // exclusive over blocks
    if (l == NB - 1) rowptr[NN] = x;                // grand total = EE
}

__global__ void scan_add(int* __restrict__ rowptr, const int* __restrict__ bsum) {
    int idx = blockIdx.x * blockDim.x + threadIdx.x;
    if (idx < NN) rowptr[idx] += bsum[idx >> 10];
}

// ---------------- CSR bucket fill ----------------
__global__ void fill_csr(const int* __restrict__ src, const int* __restrict__ dst,
                         const int* __restrict__ rowptr, int* __restrict__ cursor,
                         int* __restrict__ csr_src) {
    int e = blockIdx.x * blockDim.x + threadIdx.x;
    if (e >= EE) return;
    int d = dst[e];
    int pos = atomicAdd(&cursor[d], 1);
    csr_src[rowptr[d] + pos] = src[e];
}

// ---------------- tiny precompute: Wf^T [2][256], t0/t1 [20] float2 ----------------
__global__ __launch_bounds__(256) void precompute(const float* __restrict__ W2,
                                                  const float* __restrict__ fW1,
                                                  const float* __restrict__ emb0,
                                                  const float* __restrict__ emb1,
                                                  float* __restrict__ Wft,
                                                  float2* __restrict__ t0,
                                                  float2* __restrict__ t1) {
    int k = threadIdx.x;
    float s0 = 0.f, s1 = 0.f;
    for (int m = 0; m < OUT_F; ++m) {
        float w = W2[(size_t)k * OUT_F + m];
        s0 += w * fW1[m * 2 + 0];
        s1 += w * fW1[m * 2 + 1];
    }
    Wft[k] = s0;
    Wft[256 + k] = s1;
    if (k < 20) {
        float a0 = 0.f, a1 = 0.f, b0 = 0.f, b1v = 0.f;
        for (int u = 0; u < 32; ++u) {
            float e0 = emb0[k * 32 + u], e1 = emb1[k * 32 + u];
            a0 += e0 * fW1[(130 + u) * 2 + 0];
            a1 += e0 * fW1[(130 + u) * 2 + 1];
            b0 += e1 * fW1[(162 + u) * 2 + 0];
            b1v += e1 * fW1[(162 + u) * 2 + 1];
        }
        t0[k] = make_float2(a0, a1);
        t1[k] = make_float2(b0, b1v);
    }
}

// ---------------- fused gather (fp16 rows) + relu + 2-col projection ----------------
__global__ __launch_bounds__(256) void gather_project(const _Float16* __restrict__ hs,
                                                      const int* __restrict__ rowptr,
                                                      const int* __restrict__ csr_src,
                                                      const float* __restrict__ dinv,
                                                      const float* __restrict__ b1,
                                                      const float* __restrict__ Wft,
                                                      float2* __restrict__ q) {
    int i = blockIdx.x * 4 + (threadIdx.x >> 6);
    int l = threadIdx.x & 63;
    int lf = l & 31, le = l >> 5;
    if (i >= NN) return;
    int start = rowptr[i], end = rowptr[i + 1];
    float acc[8] = {};
    int j = start;
    for (; j + 7 < end; j += 8) {
        int s0 = csr_src[j + 0 + le];
        int s1 = csr_src[j + 2 + le];
        int s2 = csr_src[j + 4 + le];
        int s3 = csr_src[j + 6 + le];
        half8v v0 = *(const half8v*)(hs + (size_t)s0 * 256 + lf * 8);
        half8v v1 = *(const half8v*)(hs + (size_t)s1 * 256 + lf * 8);
        half8v v2 = *(const half8v*)(hs + (size_t)s2 * 256 + lf * 8);
        half8v v3 = *(const half8v*)(hs + (size_t)s3 * 256 + lf * 8);
#pragma unroll
        for (int u = 0; u < 8; ++u)
            acc[u] += ((float)v0[u] + (float)v1[u]) + ((float)v2[u] + (float)v3[u]);
    }
    for (; j + le < end; j += 2) {
        int s = csr_src[j + le];
        half8v v = *(const half8v*)(hs + (size_t)s * 256 + lf * 8);
#pragma unroll
        for (int u = 0; u < 8; ++u) acc[u] += (float)v[u];
    }
#pragma unroll
    for (int u = 0; u < 8; ++u) acc[u] += __shfl_xor(acc[u], 32, 64);
    float di = dinv[i];
    half8v sv = *(const half8v*)(hs + (size_t)i * 256 + lf * 8);
    float q0 = 0.f, q1 = 0.f;
#pragma unroll
    for (int u = 0; u < 8; ++u) {
        float o = fmaxf((acc[u] + (float)sv[u]) * di + b1[lf * 8 + u], 0.f);
        q0 += o * Wft[lf * 8 + u];
        q1 += o * Wft[256 + lf * 8 + u];
    }
#pragma unroll
    for (int off = 16; off > 0; off >>= 1) {
        q0 += __shfl_xor(q0, off, 64);
        q1 += __shfl_xor(q1, off, 64);
    }
    if (l == 0) q[i] = make_float2(q0 * di, q1 * di);
}

// ---------------- gn[i] = (sum_j q[j] + q[i]) * dinv[i] ----------------
__global__ __launch_bounds__(256) void gather_gn(const float2* __restrict__ q,
                                                 const int* __restrict__ rowptr,
                                                 const int* __restrict__ csr_src,
                                                 const float* __restrict__ dinv,
                                                 float2* __restrict__ gn) {
    int i = blockIdx.x * blockDim.x + threadIdx.x;
    if (i >= NN) return;
    int start = rowptr[i], end = rowptr[i + 1];
    float a0 = 0.f, a1 = 0.f;
    for (int j = start; j < end; ++j) {
        float2 v = q[csr_src[j]];
        a0 += v.x;
        a1 += v.y;
    }
    float2 self = q[i];
    float di = dinv[i];
    gn[i] = make_float2((a0 + self.x) * di, (a1 + self.y) * di);
}

// ---------------- final edge kernel ----------------
__global__ __launch_bounds__(256) void edge_out(const float2* __restrict__ gn,
                                                const int* __restrict__ src,
                                                const int* __restrict__ dst,
                                                const int2* __restrict__ ecat,
                                                const float2* __restrict__ ev,
                                                const float* __restrict__ fW1,
                                                const float2* __restrict__ t0,
                                                const float2* __restrict__ t1,
                                                const float* __restrict__ fb1,
                                                const float* __restrict__ fW2,
                                                const float* __restrict__ fb2,
                                                float2* __restrict__ out) {
    int e = blockIdx.x * blockDim.x + threadIdx.x;
    if (e >= EE) return;
    int s = src[e], d = dst[e];
    float2 gs = gn[s], gd = gn[d];
    int2 c = ecat[e];
    float2 v = ev[e];
    float2 e0 = t0[c.x], e1 = t1[c.y];
    float z0 = gs.x - gd.x + v.x * fW1[128 * 2 + 0] + v.y * fW1[129 * 2 + 0] + e0.x + e1.x;
    float z1 = gs.y - gd.y + v.x * fW1[128 * 2 + 1] + v.y * fW1[129 * 2 + 1] + e0.y + e1.y;
    float y0 = fmaxf(z0 + fb1[0], 0.f);
    float y1 = fmaxf(z1 + fb1[1], 0.f);
    out[e] = make_float2(y0 * fW2[0] + y1 * fW2[2] + fb2[0],
                         y0 * fW2[1] + y1 * fW2[3] + fb2[1]);
}

extern "C" void kernel_launch(void* const* d_in, const int* in_sizes, int n_in,
                              void* d_out, int out_size, void* d_ws, size_t ws_size,
                              hipStream_t stream) {
    const float* x    = (const float*)d_in[0];
    const int*   eidx = (const int*)d_in[1];
    const int*   src  = eidx;
    const int*   dst  = eidx + EE;
    const int*   ecat = (const int*)d_in[2];
    const float* ev   = (const float*)d_in[3];
    const float* W1   = (const float*)d_in[4];
    const float* b1   = (const float*)d_in[5];
    const float* W2   = (const float*)d_in[6];
    // b2 (d_in[7]) cancels in gn[s]-gn[d]; unused.
    const float* emb0 = (const float*)d_in[8];
    const float* emb1 = (const float*)d_in[9];
    const float* fW1  = (const float*)d_in[10];
    const float* fb1  = (const float*)d_in[11];
    const float* fW2  = (const float*)d_in[12];
    const float* fb2  = (const float*)d_in[13];
    float* out = (float*)d_out;

    char* ws = (char*)d_ws;
    size_t off = 0;
    auto alloc = [&](size_t bytes) {
        void* p = ws + off;
        off = (off + bytes + 255) & ~(size_t)255;
        return p;
    };
    int*      deg     = (int*)alloc((size_t)NN * 4);
    float*    dinv    = (float*)alloc((size_t)NN * 4);
    int*      rowptr  = (int*)alloc((size_t)(NN + 1) * 4);
    int*      cursor  = (int*)alloc((size_t)NN * 4);
    int*      bsum    = (int*)alloc((size_t)NB * 4);
    int*      csr_src = (int*)alloc((size_t)EE * 4);
    _Float16* h1s     = (_Float16*)alloc((size_t)NN * HID_F * 2);  // 25.6 MB fp16
    float2*   q       = (float2*)alloc((size_t)NN * 8);
    float2*   gn      = (float2*)alloc((size_t)NN * 8);
    float*    Wft     = (float*)alloc(512 * 4);
    float2*   t0      = (float2*)alloc(20 * 8);
    float2*   t1      = (float2*)alloc(20 * 8);

    hipMemsetAsync(deg, 0, (size_t)NN * 4, stream);
    hipMemsetAsync(cursor, 0, (size_t)NN * 4, stream);

    // graph structure
    deg_count<<<(EE + 255) / 256, 256, 0, stream>>>(dst, deg);
    make_dinv<<<(NN + 255) / 256, 256, 0, stream>>>(deg, dinv);
    scan_partial<<<NB, 1024, 0, stream>>>(deg, rowptr, bsum);
    scan_bsum<<<1, 64, 0, stream>>>(bsum, rowptr);
    scan_add<<<(NN + 255) / 256, 256, 0, stream>>>(rowptr, bsum);
    fill_csr<<<(EE + 255) / 256, 256, 0, stream>>>(src, dst, rowptr, cursor, csr_src);

    // tiny projections
    precompute<<<1, 256, 0, stream>>>(W2, fW1, emb0, emb1, Wft, t0, t1);

    // layer 1 GEMM (MFMA fp16): h1s = fp16((x @ W1) * dinv)
    {
        dim3 g(2, (NN + 127) / 128);
        gemm1_mfma<<<g, 256, 0, stream>>>(x, W1, dinv, h1s, NN);
    }
    // fused gather + relu + project -> q [N,2]
    gather_project<<<(NN + 3) / 4, 256, 0, stream>>>(
        h1s, rowptr, csr_src, dinv, b1, Wft, q);
    // gn [N,2]
    gather_gn<<<(NN + 255) / 256, 256, 0, stream>>>(q, rowptr, csr_src, dinv, gn);
    // edges
    edge_out<<<(EE + 255) / 256, 256, 0, stream>>>(
        gn, src, dst, (const int2*)ecat, (const float2*)ev,
        fW1, t0, t1, fb1, fW2, fb2, (float2*)out);
}

// Round 6
// 209.414 us; speedup vs baseline: 21.6870x; 1.0612x over previous
//
#include <hip/hip_runtime.h>

#define NN 50000
#define EE 800000
#define IN_F 256
#define HID_F 256
#define OUT_F 128
#define NB ((NN + 1023) / 1024)   // 49 scan blocks

typedef _Float16 half8v __attribute__((ext_vector_type(8)));
typedef _Float16 half4v __attribute__((ext_vector_type(4)));
typedef float f32x4 __attribute__((ext_vector_type(4)));

// ---------------- W1 [k][n] f32 -> BT [n][k] fp16 (LDS-tiled transpose) ----------------
__global__ __launch_bounds__(256) void transposeW(const float* __restrict__ W,
                                                  _Float16* __restrict__ BT) {
    __shared__ float T[64][65];
    int k0 = blockIdx.y * 64, n0 = blockIdx.x * 64;
    int t = threadIdx.x;
#pragma unroll
    for (int i = 0; i < 16; ++i) {
        int r = i * 4 + (t >> 6), c = t & 63;          // coalesced read of W row k0+r
        T[r][c] = W[(size_t)(k0 + r) * 256 + n0 + c];
    }
    __syncthreads();
#pragma unroll
    for (int i = 0; i < 16; ++i) {
        int n = i * 4 + (t >> 6), k = t & 63;          // coalesced write of BT row n0+n
        BT[(size_t)(n0 + n) * 256 + k0 + k] = (_Float16)T[k][n];
    }
}

// ---------------- MFMA fp16 GEMM: C[M,256] = fp16((A[M,256] @ W1) * dinv[m]) ----------------
// BM=64, BN=128, BK=32; 4 waves in 2x2, wave tile 32x64; grid (2, M/64)
__global__ __launch_bounds__(256) void gemm1_mfma(const float* __restrict__ A,
                                                  const _Float16* __restrict__ BT,
                                                  const float* __restrict__ dinv,
                                                  _Float16* __restrict__ C, int M) {
    const int BK = 32;
    __shared__ _Float16 Ah[64][BK + 8];    // 5 KB
    __shared__ _Float16 Bh[128][BK + 8];   // 10 KB
    int tid = threadIdx.x;
    int bm = blockIdx.y * 64, bn = blockIdx.x * 128;
    int w = tid >> 6, l = tid & 63;
    int wr = w >> 1, wc = w & 1;           // 2x2 wave grid
    int lr = l & 15, lg = l >> 4;
    f32x4 acc[2][4] = {};

    for (int k0 = 0; k0 < 256; k0 += BK) {
        // stage A: 64 rows x 32 k, f32 -> fp16. 512 float4 loads, 2/thread.
#pragma unroll
        for (int i = 0; i < 2; ++i) {
            int idx = tid + i * 256;
            int r = idx >> 3, oc = idx & 7;
            int gm = bm + r;
            float4 v = make_float4(0.f, 0.f, 0.f, 0.f);
            if (gm < M) v = *(const float4*)&A[(size_t)gm * 256 + k0 + oc * 4];
            half4v h;
            h[0] = (_Float16)v.x; h[1] = (_Float16)v.y;
            h[2] = (_Float16)v.z; h[3] = (_Float16)v.w;
            *(half4v*)&Ah[r][oc * 4] = h;
        }
        // stage BT: 128 rows x 32 k fp16, coalesced 16B loads, 2/thread.
#pragma unroll
        for (int i = 0; i < 2; ++i) {
            int idx = tid + i * 256;
            int n = idx >> 2, ko = idx & 3;
            half8v v = *(const half8v*)&BT[(size_t)(bn + n) * 256 + k0 + ko * 8];
            *(half8v*)&Bh[n][ko * 8] = v;
        }
        __syncthreads();
        half8v a[2], b[4];
#pragma unroll
        for (int mf = 0; mf < 2; ++mf)
            a[mf] = *(const half8v*)&Ah[wr * 32 + mf * 16 + lr][lg * 8];
#pragma unroll
        for (int nf = 0; nf < 4; ++nf)
            b[nf] = *(const half8v*)&Bh[wc * 64 + nf * 16 + lr][lg * 8];
#pragma unroll
        for (int mf = 0; mf < 2; ++mf)
#pragma unroll
            for (int nf = 0; nf < 4; ++nf)
                acc[mf][nf] = __builtin_amdgcn_mfma_f32_16x16x32_f16(a[mf], b[nf], acc[mf][nf], 0, 0, 0);
        __syncthreads();
    }
    // epilogue: D row = (lane>>4)*4 + reg, col = lane&15
#pragma unroll
    for (int mf = 0; mf < 2; ++mf) {
#pragma unroll
        for (int reg = 0; reg < 4; ++reg) {
            int gr = bm + wr * 32 + mf * 16 + lg * 4 + reg;
            if (gr < M) {
                float sc = dinv[gr];
#pragma unroll
                for (int nf = 0; nf < 4; ++nf)
                    C[(size_t)gr * 256 + bn + wc * 64 + nf * 16 + lr] =
                        (_Float16)(acc[mf][nf][reg] * sc);
            }
        }
    }
}

// ---------------- degree + dinv ----------------
__global__ void deg_count(const int* __restrict__ dst, int* __restrict__ deg) {
    int e = blockIdx.x * blockDim.x + threadIdx.x;
    if (e < EE) atomicAdd(&deg[dst[e]], 1);
}

__global__ void make_dinv(const int* __restrict__ deg, float* __restrict__ dinv) {
    int i = blockIdx.x * blockDim.x + threadIdx.x;
    if (i < NN) dinv[i] = rsqrtf((float)deg[i] + 1.0f);
}

// ---------------- 3-kernel parallel scan: deg -> rowptr ----------------
__global__ __launch_bounds__(1024) void scan_partial(const int* __restrict__ deg,
                                                     int* __restrict__ rowptr,
                                                     int* __restrict__ bsum) {
    __shared__ int wsum[16];
    int tid = threadIdx.x, lane = tid & 63, w = tid >> 6;
    int idx = blockIdx.x * 1024 + tid;
    int v = (idx < NN) ? deg[idx] : 0;
    int x = v;
#pragma unroll
    for (int off = 1; off < 64; off <<= 1) {
        int t = __shfl_up(x, off, 64);
        if (lane >= off) x += t;
    }
    if (lane == 63) wsum[w] = x;
    __syncthreads();
    if (w == 0) {
        int s = (lane < 16) ? wsum[lane] : 0;
#pragma unroll
        for (int off = 1; off < 16; off <<= 1) {
            int t = __shfl_up(s, off, 64);
            if (lane >= off) s += t;
        }
        if (lane < 16) wsum[lane] = s;
    }
    __syncthreads();
    int wpre = (w == 0) ? 0 : wsum[w - 1];
    if (idx < NN) rowptr[idx] = wpre + (x - v);     // exclusive within block
    if (tid == 0) bsum[blockIdx.x] = wsum[15];      // block total
}

__global__ __launch_bounds__(64) void scan_bsum(int* __restrict__ bsum,
                                                int* __restrict__ rowptr) {
    int l = threadIdx.x;
    int v = (l < NB) ? bsum[l] : 0;
    int x = v;
#pragma unroll
    for (int off = 1; off < 64; off <<= 1) {
        int t = __shfl_up(x, off, 64);
        if (l >= off) x += t;
    }
    if (l < NB) bsum[l] = x - v;                    // exclusive over blocks
    if (l == NB - 1) rowptr[NN] = x;                // grand total = EE
}

__global__ void scan_add(int* __restrict__ rowptr, const int* __restrict__ bsum) {
    int idx = blockIdx.x * blockDim.x + threadIdx.x;
    if (idx < NN) rowptr[idx] += bsum[idx >> 10];
}

// ---------------- CSR bucket fill ----------------
__global__ void fill_csr(const int* __restrict__ src, const int* __restrict__ dst,
                         const int* __restrict__ rowptr, int* __restrict__ cursor,
                         int* __restrict__ csr_src) {
    int e = blockIdx.x * blockDim.x + threadIdx.x;
    if (e >= EE) return;
    int d = dst[e];
    int pos = atomicAdd(&cursor[d], 1);
    csr_src[rowptr[d] + pos] = src[e];
}

// ---------------- tiny precompute: Wf^T [2][256], t0/t1 [20] float2 ----------------
__global__ __launch_bounds__(256) void precompute(const float* __restrict__ W2,
                                                  const float* __restrict__ fW1,
                                                  const float* __restrict__ emb0,
                                                  const float* __restrict__ emb1,
                                                  float* __restrict__ Wft,
                                                  float2* __restrict__ t0,
                                                  float2* __restrict__ t1) {
    int k = threadIdx.x;
    float s0 = 0.f, s1 = 0.f;
    for (int m = 0; m < OUT_F; ++m) {
        float w = W2[(size_t)k * OUT_F + m];
        s0 += w * fW1[m * 2 + 0];
        s1 += w * fW1[m * 2 + 1];
    }
    Wft[k] = s0;
    Wft[256 + k] = s1;
    if (k < 20) {
        float a0 = 0.f, a1 = 0.f, b0 = 0.f, b1v = 0.f;
        for (int u = 0; u < 32; ++u) {
            float e0 = emb0[k * 32 + u], e1 = emb1[k * 32 + u];
            a0 += e0 * fW1[(130 + u) * 2 + 0];
            a1 += e0 * fW1[(130 + u) * 2 + 1];
            b0 += e1 * fW1[(162 + u) * 2 + 0];
            b1v += e1 * fW1[(162 + u) * 2 + 1];
        }
        t0[k] = make_float2(a0, a1);
        t1[k] = make_float2(b0, b1v);
    }
}

// ---------------- fused gather (fp16 rows) + relu + 2-col projection ----------------
__global__ __launch_bounds__(256) void gather_project(const _Float16* __restrict__ hs,
                                                      const int* __restrict__ rowptr,
                                                      const int* __restrict__ csr_src,
                                                      const float* __restrict__ dinv,
                                                      const float* __restrict__ b1,
                                                      const float* __restrict__ Wft,
                                                      float2* __restrict__ q) {
    int i = blockIdx.x * 4 + (threadIdx.x >> 6);
    int l = threadIdx.x & 63;
    int lf = l & 31, le = l >> 5;
    if (i >= NN) return;
    int start = rowptr[i], end = rowptr[i + 1];
    float acc[8] = {};
    int j = start;
    for (; j + 7 < end; j += 8) {
        int s0 = csr_src[j + 0 + le];
        int s1 = csr_src[j + 2 + le];
        int s2 = csr_src[j + 4 + le];
        int s3 = csr_src[j + 6 + le];
        half8v v0 = *(const half8v*)(hs + (size_t)s0 * 256 + lf * 8);
        half8v v1 = *(const half8v*)(hs + (size_t)s1 * 256 + lf * 8);
        half8v v2 = *(const half8v*)(hs + (size_t)s2 * 256 + lf * 8);
        half8v v3 = *(const half8v*)(hs + (size_t)s3 * 256 + lf * 8);
#pragma unroll
        for (int u = 0; u < 8; ++u)
            acc[u] += ((float)v0[u] + (float)v1[u]) + ((float)v2[u] + (float)v3[u]);
    }
    for (; j + le < end; j += 2) {
        int s = csr_src[j + le];
        half8v v = *(const half8v*)(hs + (size_t)s * 256 + lf * 8);
#pragma unroll
        for (int u = 0; u < 8; ++u) acc[u] += (float)v[u];
    }
#pragma unroll
    for (int u = 0; u < 8; ++u) acc[u] += __shfl_xor(acc[u], 32, 64);
    float di = dinv[i];
    half8v sv = *(const half8v*)(hs + (size_t)i * 256 + lf * 8);
    float q0 = 0.f, q1 = 0.f;
#pragma unroll
    for (int u = 0; u < 8; ++u) {
        float o = fmaxf((acc[u] + (float)sv[u]) * di + b1[lf * 8 + u], 0.f);
        q0 += o * Wft[lf * 8 + u];
        q1 += o * Wft[256 + lf * 8 + u];
    }
#pragma unroll
    for (int off = 16; off > 0; off >>= 1) {
        q0 += __shfl_xor(q0, off, 64);
        q1 += __shfl_xor(q1, off, 64);
    }
    if (l == 0) q[i] = make_float2(q0 * di, q1 * di);
}

// ---------------- gn[i] = (sum_j q[j] + q[i]) * dinv[i] ----------------
__global__ __launch_bounds__(256) void gather_gn(const float2* __restrict__ q,
                                                 const int* __restrict__ rowptr,
                                                 const int* __restrict__ csr_src,
                                                 const float* __restrict__ dinv,
                                                 float2* __restrict__ gn) {
    int i = blockIdx.x * blockDim.x + threadIdx.x;
    if (i >= NN) return;
    int start = rowptr[i], end = rowptr[i + 1];
    float a0 = 0.f, a1 = 0.f;
    for (int j = start; j < end; ++j) {
        float2 v = q[csr_src[j]];
        a0 += v.x;
        a1 += v.y;
    }
    float2 self = q[i];
    float di = dinv[i];
    gn[i] = make_float2((a0 + self.x) * di, (a1 + self.y) * di);
}

// ---------------- final edge kernel ----------------
__global__ __launch_bounds__(256) void edge_out(const float2* __restrict__ gn,
                                                const int* __restrict__ src,
                                                const int* __restrict__ dst,
                                                const int2* __restrict__ ecat,
                                                const float2* __restrict__ ev,
                                                const float* __restrict__ fW1,
                                                const float2* __restrict__ t0,
                                                const float2* __restrict__ t1,
                                                const float* __restrict__ fb1,
                                                const float* __restrict__ fW2,
                                                const float* __restrict__ fb2,
                                                float2* __restrict__ out) {
    int e = blockIdx.x * blockDim.x + threadIdx.x;
    if (e >= EE) return;
    int s = src[e], d = dst[e];
    float2 gs = gn[s], gd = gn[d];
    int2 c = ecat[e];
    float2 v = ev[e];
    float2 e0 = t0[c.x], e1 = t1[c.y];
    float z0 = gs.x - gd.x + v.x * fW1[128 * 2 + 0] + v.y * fW1[129 * 2 + 0] + e0.x + e1.x;
    float z1 = gs.y - gd.y + v.x * fW1[128 * 2 + 1] + v.y * fW1[129 * 2 + 1] + e0.y + e1.y;
    float y0 = fmaxf(z0 + fb1[0], 0.f);
    float y1 = fmaxf(z1 + fb1[1], 0.f);
    out[e] = make_float2(y0 * fW2[0] + y1 * fW2[2] + fb2[0],
                         y0 * fW2[1] + y1 * fW2[3] + fb2[1]);
}

extern "C" void kernel_launch(void* const* d_in, const int* in_sizes, int n_in,
                              void* d_out, int out_size, void* d_ws, size_t ws_size,
                              hipStream_t stream) {
    const float* x    = (const float*)d_in[0];
    const int*   eidx = (const int*)d_in[1];
    const int*   src  = eidx;
    const int*   dst  = eidx + EE;
    const int*   ecat = (const int*)d_in[2];
    const float* ev   = (const float*)d_in[3];
    const float* W1   = (const float*)d_in[4];
    const float* b1   = (const float*)d_in[5];
    const float* W2   = (const float*)d_in[6];
    // b2 (d_in[7]) cancels in gn[s]-gn[d]; unused.
    const float* emb0 = (const float*)d_in[8];
    const float* emb1 = (const float*)d_in[9];
    const float* fW1  = (const float*)d_in[10];
    const float* fb1  = (const float*)d_in[11];
    const float* fW2  = (const float*)d_in[12];
    const float* fb2  = (const float*)d_in[13];
    float* out = (float*)d_out;

    char* ws = (char*)d_ws;
    size_t off = 0;
    auto alloc = [&](size_t bytes) {
        void* p = ws + off;
        off = (off + bytes + 255) & ~(size_t)255;
        return p;
    };
    int*      deg     = (int*)alloc((size_t)NN * 4);
    float*    dinv    = (float*)alloc((size_t)NN * 4);
    int*      rowptr  = (int*)alloc((size_t)(NN + 1) * 4);
    int*      cursor  = (int*)alloc((size_t)NN * 4);
    int*      bsum    = (int*)alloc((size_t)NB * 4);
    int*      csr_src = (int*)alloc((size_t)EE * 4);
    _Float16* W1T     = (_Float16*)alloc((size_t)256 * 256 * 2);   // 128 KB fp16
    _Float16* h1s     = (_Float16*)alloc((size_t)NN * HID_F * 2);  // 25.6 MB fp16
    float2*   q       = (float2*)alloc((size_t)NN * 8);
    float2*   gn      = (float2*)alloc((size_t)NN * 8);
    float*    Wft     = (float*)alloc(512 * 4);
    float2*   t0      = (float2*)alloc(20 * 8);
    float2*   t1      = (float2*)alloc(20 * 8);

    hipMemsetAsync(deg, 0, (size_t)NN * 4, stream);
    hipMemsetAsync(cursor, 0, (size_t)NN * 4, stream);

    // graph structure
    deg_count<<<(EE + 255) / 256, 256, 0, stream>>>(dst, deg);
    make_dinv<<<(NN + 255) / 256, 256, 0, stream>>>(deg, dinv);
    scan_partial<<<NB, 1024, 0, stream>>>(deg, rowptr, bsum);
    scan_bsum<<<1, 64, 0, stream>>>(bsum, rowptr);
    scan_add<<<(NN + 255) / 256, 256, 0, stream>>>(rowptr, bsum);
    fill_csr<<<(EE + 255) / 256, 256, 0, stream>>>(src, dst, rowptr, cursor, csr_src);

    // tiny projections + W1 transpose
    precompute<<<1, 256, 0, stream>>>(W2, fW1, emb0, emb1, Wft, t0, t1);
    {
        dim3 g(4, 4);
        transposeW<<<g, 256, 0, stream>>>(W1, W1T);
    }

    // layer 1 GEMM (MFMA fp16): h1s = fp16((x @ W1) * dinv)
    {
        dim3 g(2, (NN + 63) / 64);
        gemm1_mfma<<<g, 256, 0, stream>>>(x, W1T, dinv, h1s, NN);
    }
    // fused gather + relu + project -> q [N,2]
    gather_project<<<(NN + 3) / 4, 256, 0, stream>>>(
        h1s, rowptr, csr_src, dinv, b1, Wft, q);
    // gn [N,2]
    gather_gn<<<(NN + 255) / 256, 256, 0, stream>>>(q, rowptr, csr_src, dinv, gn);
    // edges
    edge_out<<<(EE + 255) / 256, 256, 0, stream>>>(
        gn, src, dst, (const int2*)ecat, (const float2*)ev,
        fW1, t0, t1, fb1, fW2, fb2, (float2*)out);
}